// Round 1
// baseline (713.148 us; speedup 1.0000x reference)
//
#include <hip/hip_runtime.h>
#include <cstdint>

// Problem constants: B=32, N=4096, C=768, H=12, hd=64, L=32, chunk=24
// Key identity: out[b,l,c'] = (sum_n attn[b,l,n] x[b,n,:]) . v_w[l*24+c',:] + v_b
// (valid because sum_n attn = 1 and the value projection is linear), which
// collapses the 154 GF value-GEMM into a 6.4 GF weighted sum.

typedef short bf16x8 __attribute__((ext_vector_type(8)));
typedef float f32x4 __attribute__((ext_vector_type(4)));

#define MFMA16(a, b, c) __builtin_amdgcn_mfma_f32_16x16x32_bf16((a), (b), (c), 0, 0, 0)

__device__ __forceinline__ unsigned short f2bf(float f) {
    union { float f; uint32_t u; } v; v.f = f;
    uint32_t u = v.u;
    u += 0x7FFFu + ((u >> 16) & 1u);   // round-to-nearest-even
    return (unsigned short)(u >> 16);
}

// ---------------------------------------------------------------------------
// K1 (MODE 0): per (b, 64-row n-tile) compute S[h][l][n] = (q*0.125)·k via
//   bf16 MFMA, exp, and accumulate sums[b,h,l] (global atomicAdd).
// K3a (MODE 1): recompute S, produce W[b][l][n] = sum_h exp(S)*rs[b,h,l] (bf16).
// grid = 32*64 blocks, 256 threads (4 waves; wave w owns n-subtile w*16..w*16+15).
// MFMA 16x16x32 layouts: A[m=lane&15][k=quad*8+j], B[k=quad*8+j][n=lane&15],
//   D col=lane&15, row=quad*4+reg  (guide §3, m89/m120-verified).
// ---------------------------------------------------------------------------
template <int MODE>
__global__ __launch_bounds__(256)
void attn_sw_kernel(const float* __restrict__ x, const float* __restrict__ latent,
                    float* __restrict__ g_sums, const float* __restrict__ g_rs,
                    unsigned short* __restrict__ g_W)
{
    const int b   = blockIdx.x >> 6;
    const int n0  = (blockIdx.x & 63) << 6;
    const int tid = threadIdx.x;
    const int wv  = tid >> 6;
    const int lane = tid & 63;
    const int quad = lane >> 4;
    const int lc   = lane & 15;

    // +8-short row pad: 16B frag reads land on rotating banks (2-way max = free)
    __shared__ unsigned short q_lds[32][72];
    __shared__ unsigned short x_lds[64][72];
    __shared__ float red_lds[384];            // MODE0: partial sums; MODE1: rs

    if (MODE == 0) {
        for (int i = tid; i < 384; i += 256) red_lds[i] = 0.0f;
    } else {
        for (int i = tid; i < 384; i += 256) red_lds[i] = g_rs[b * 384 + i];
    }

    float acc0[4] = {0.f, 0.f, 0.f, 0.f};     // MODE1: W accum, l-tile 0
    float acc1[4] = {0.f, 0.f, 0.f, 0.f};     // MODE1: W accum, l-tile 1

    for (int h = 0; h < 12; ++h) {
        __syncthreads();  // protect previous iteration's LDS reads (and init)
        // stage q (pre-scaled by hd^-0.5 = 0.125): 32 l x 64 d, fp32->bf16
        for (int i = tid; i < 512; i += 256) {
            int l = i >> 4, f4 = i & 15;
            float4 qv = *(const float4*)&latent[l * 768 + h * 64 + f4 * 4];
            ushort4 qb;
            qb.x = f2bf(qv.x * 0.125f); qb.y = f2bf(qv.y * 0.125f);
            qb.z = f2bf(qv.z * 0.125f); qb.w = f2bf(qv.w * 0.125f);
            *(ushort4*)&q_lds[l][f4 * 4] = qb;
        }
        // stage x head-slice: 64 n x 64 d (256B contiguous per row, coalesced)
        for (int i = tid; i < 1024; i += 256) {
            int n = i >> 4, f4 = i & 15;
            float4 xv = *(const float4*)&x[(b * 4096 + n0 + n) * 768 + h * 64 + f4 * 4];
            ushort4 xb;
            xb.x = f2bf(xv.x); xb.y = f2bf(xv.y);
            xb.z = f2bf(xv.z); xb.w = f2bf(xv.w);
            *(ushort4*)&x_lds[n][f4 * 4] = xb;
        }
        __syncthreads();

        bf16x8 a00 = *(const bf16x8*)&q_lds[lc][quad * 8];
        bf16x8 a01 = *(const bf16x8*)&q_lds[lc][32 + quad * 8];
        bf16x8 a10 = *(const bf16x8*)&q_lds[16 + lc][quad * 8];
        bf16x8 a11 = *(const bf16x8*)&q_lds[16 + lc][32 + quad * 8];
        bf16x8 b0  = *(const bf16x8*)&x_lds[wv * 16 + lc][quad * 8];
        bf16x8 b1  = *(const bf16x8*)&x_lds[wv * 16 + lc][32 + quad * 8];

        f32x4 c0 = {0.f, 0.f, 0.f, 0.f};
        f32x4 c1 = {0.f, 0.f, 0.f, 0.f};
        c0 = MFMA16(a00, b0, c0);  // l-tile 0, k = d 0..31
        c0 = MFMA16(a01, b1, c0);  // l-tile 0, k = d 32..63
        c1 = MFMA16(a10, b0, c1);  // l-tile 1
        c1 = MFMA16(a11, b1, c1);

        #pragma unroll
        for (int r = 0; r < 4; ++r) {
            float e0 = __expf(c0[r]);          // |S| <~ 0.15: exp w/o max-sub is safe
            float e1 = __expf(c1[r]);
            if (MODE == 0) {
                float v0 = e0, v1 = e1;
                #pragma unroll
                for (int m = 1; m < 16; m <<= 1) {   // reduce over the 16 n-columns
                    v0 += __shfl_xor(v0, m);
                    v1 += __shfl_xor(v1, m);
                }
                if (lc == 0) {
                    atomicAdd(&red_lds[h * 32 + quad * 4 + r], v0);
                    atomicAdd(&red_lds[h * 32 + 16 + quad * 4 + r], v1);
                }
            } else {
                acc0[r] += e0 * red_lds[h * 32 + quad * 4 + r];
                acc1[r] += e1 * red_lds[h * 32 + 16 + quad * 4 + r];
            }
        }
    }

    if (MODE == 0) {
        __syncthreads();
        for (int i = tid; i < 384; i += 256)
            atomicAdd(&g_sums[b * 384 + i], red_lds[i]);
    } else {
        const int n = n0 + wv * 16 + lc;
        #pragma unroll
        for (int r = 0; r < 4; ++r) {
            g_W[(b * 32 + quad * 4 + r) * 4096 + n]      = f2bf(acc0[r]);
            g_W[(b * 32 + 16 + quad * 4 + r) * 4096 + n] = f2bf(acc1[r]);
        }
    }
}

// ---------------------------------------------------------------------------
// K2: rs[b,h,l] = (1/12) / sums[b,h,l]
// ---------------------------------------------------------------------------
__global__ __launch_bounds__(256)
void invert_kernel(const float* __restrict__ sums, float* __restrict__ rs)
{
    int i = blockIdx.x * 256 + threadIdx.x;
    if (i < 12288) rs[i] = 1.0f / (12.0f * sums[i]);
}

// ---------------------------------------------------------------------------
// K3: y[g][b][l][c] partial = sum_{n in g-range} W[b][l][n] * x[b][n][c]
// Single-wave blocks, NO LDS, NO barriers: A-frags are 16B loads from W
// (L2-resident, 8 MB); B-frags are 8 scalar fp32 loads of x (each instr =
// 4 fully-dense 64B lines across the wave) converted to bf16 in-register.
// grid = 32 b * 12 c-tiles(64) * 4 n-groups(1024) = 1536 blocks of 64.
// ---------------------------------------------------------------------------
__global__ __launch_bounds__(64)
void yacc_kernel(const float* __restrict__ x, const unsigned short* __restrict__ W,
                 float* __restrict__ yws)
{
    const int bx  = blockIdx.x;
    const int b   = bx / 48;
    const int rem = bx - b * 48;
    const int ct  = rem % 12;
    const int g   = rem / 12;
    const int lane = threadIdx.x;
    const int quad = lane >> 4;
    const int lc   = lane & 15;
    const int c0   = ct * 64;
    const int nb   = g * 1024;

    const float* xb = x + b * 4096 * 768;
    const unsigned short* Wb = W + b * 32 * 4096;

    f32x4 acc[2][4];
    #pragma unroll
    for (int t = 0; t < 2; ++t)
        #pragma unroll
        for (int s = 0; s < 4; ++s) acc[t][s] = (f32x4){0.f, 0.f, 0.f, 0.f};

    for (int kk = 0; kk < 1024; kk += 32) {
        const int n = nb + kk + quad * 8;
        bf16x8 a0 = *(const bf16x8*)&Wb[lc * 4096 + n];
        bf16x8 a1 = *(const bf16x8*)&Wb[(16 + lc) * 4096 + n];
        #pragma unroll
        for (int s = 0; s < 4; ++s) {
            const float* xp = xb + n * 768 + c0 + s * 16 + lc;
            bf16x8 bb;
            #pragma unroll
            for (int j = 0; j < 8; ++j) bb[j] = (short)f2bf(xp[j * 768]);
            acc[0][s] = MFMA16(a0, bb, acc[0][s]);
            acc[1][s] = MFMA16(a1, bb, acc[1][s]);
        }
    }

    float* yp = yws + ((g * 32 + b) * 32) * 768;
    #pragma unroll
    for (int t = 0; t < 2; ++t)
        #pragma unroll
        for (int s = 0; s < 4; ++s)
            #pragma unroll
            for (int r = 0; r < 4; ++r) {
                int l = t * 16 + quad * 4 + r;
                int c = c0 + s * 16 + lc;
                yp[l * 768 + c] = acc[t][s][r];
            }
}

// ---------------------------------------------------------------------------
// K4: out[b, l*24+i] = sum_c y[b,l,c] * v_w[l*24+i, c] + v_b[l*24+i]
// (y = sum of the 4 n-group partials). fp32 throughout. 1024 blocks (b,l).
// ---------------------------------------------------------------------------
__global__ __launch_bounds__(256)
void out_kernel(const float* __restrict__ yws, const float* __restrict__ vw,
                const float* __restrict__ vb, float* __restrict__ out)
{
    const int b = blockIdx.x >> 5;
    const int l = blockIdx.x & 31;
    const int tid = threadIdx.x;
    __shared__ float y_lds[768];
    for (int c = tid; c < 768; c += 256) {
        float v = 0.f;
        #pragma unroll
        for (int g = 0; g < 4; ++g)
            v += yws[((g * 32 + b) * 32 + l) * 768 + c];
        y_lds[c] = v;
    }
    __syncthreads();
    const int wv = tid >> 6, lane = tid & 63;
    for (int i = wv; i < 24; i += 4) {
        const int row = l * 24 + i;
        const float* wr = vw + row * 768;
        float p = 0.f;
        #pragma unroll
        for (int j = 0; j < 12; ++j)
            p += y_lds[j * 64 + lane] * wr[j * 64 + lane];
        #pragma unroll
        for (int m = 1; m < 64; m <<= 1) p += __shfl_xor(p, m);
        if (lane == 0) out[b * 768 + row] = p + vb[row];
    }
}

// ---------------------------------------------------------------------------
extern "C" void kernel_launch(void* const* d_in, const int* in_sizes, int n_in,
                              void* d_out, int out_size, void* d_ws, size_t ws_size,
                              hipStream_t stream)
{
    const float* x      = (const float*)d_in[0];  // [32,4096,768]
    const float* latent = (const float*)d_in[1];  // [1,32,768]
    const float* vw     = (const float*)d_in[2];  // [768,768]
    const float* vb     = (const float*)d_in[3];  // [768]
    float* out = (float*)d_out;                   // [32,1,768] -> 24576 f32

    // ws layout (needs ~20.1 MB):
    //   [0,      49152)  sums  f32[32*12*32]   (zero-init, atomicAdd target)
    //   [49152,  98304)  rs    f32[32*12*32]
    //   [98304,  8486912)  W   bf16[32*32*4096]  (8 MB)
    //   [8486912, 21069824) y  f32[4][32][32][768] (12 MB partials)
    char* ws = (char*)d_ws;
    float*          sums = (float*)ws;
    float*          rs   = (float*)(ws + 49152);
    unsigned short* W    = (unsigned short*)(ws + 98304);
    float*          yws  = (float*)(ws + 98304 + 8388608);

    hipMemsetAsync(sums, 0, 12288 * sizeof(float), stream);
    attn_sw_kernel<0><<<dim3(2048), dim3(256), 0, stream>>>(x, latent, sums, nullptr, nullptr);
    invert_kernel<<<dim3(48), dim3(256), 0, stream>>>(sums, rs);
    attn_sw_kernel<1><<<dim3(2048), dim3(256), 0, stream>>>(x, latent, nullptr, rs, W);
    yacc_kernel<<<dim3(1536), dim3(64), 0, stream>>>(x, W, yws);
    out_kernel<<<dim3(1024), dim3(256), 0, stream>>>(yws, vw, vb, out);
}

// Round 2
// 689.596 us; speedup vs baseline: 1.0342x; 1.0342x over previous
//
#include <hip/hip_runtime.h>
#include <cstdint>

// Problem: B=32, N=4096, C=768, H=12, hd=64, L=32, chunk=24
// Identity: out[b,l,c'] = (sum_n attn[b,l,n] x[b,n,:]) . v_w[l*24+c',:] + v_b
// (sum_n attn = 1, value proj is linear) -> 154 GF value-GEMM collapses to a
// 13 GF weighted sum. Pipeline (2 full x passes + E round-trip):
//   K1:  S = (q*0.125)Â·k per (b,h,n-tile) via bf16 MFMA; E=exp(S) -> ws (bf16, 100 MB)
//   KW:  per (b,l): sums_h = sum_n E; rs = 1/(12*sums); W[b,l,n] = sum_h rs*E (bf16)
//   K3:  y[g][b,l,c] = sum_{n in g} W[b,l,n]*x[b,n,c]  (MFMA, x pass 2)
//   K4:  out = (sum_g y) . v_w^T + v_b

typedef short bf16x8 __attribute__((ext_vector_type(8)));
typedef float f32x4 __attribute__((ext_vector_type(4)));

#define MFMA16(a, b, c) __builtin_amdgcn_mfma_f32_16x16x32_bf16((a), (b), (c), 0, 0, 0)

// pack two f32 -> (bf16(a) | bf16(b)<<16) by byte-select (truncation, 1 VALU)
__device__ __forceinline__ uint32_t pk_bf16(float a, float b) {
    return __builtin_amdgcn_perm(__float_as_uint(b), __float_as_uint(a), 0x07060302u);
}
__device__ __forceinline__ unsigned short bf16_trunc(float f) {
    return (unsigned short)(__float_as_uint(f) >> 16);
}
__device__ __forceinline__ float bf16_lo(uint32_t u) { return __uint_as_float(u << 16); }
__device__ __forceinline__ float bf16_hi(uint32_t u) { return __uint_as_float(u & 0xffff0000u); }

// ---------------------------------------------------------------------------
// K1: per (b, 64-row n-tile): for each h, S[l][n] = (q*0.125)Â·k via MFMA
// 16x16x32 (A[m=lane&15][k=quad*8+j], B[k][n=lane&15], D col=lane&15,
// row=quad*4+reg), then E = exp(S) stored bf16 at E[((b*12+h)*32+l)*4096+n].
// grid = 32*64 = 2048 blocks x 256 (wave w owns n-subtile w*16..+16).
// ---------------------------------------------------------------------------
__global__ __launch_bounds__(256)
void k1_logits(const float* __restrict__ x, const float* __restrict__ latent,
               unsigned short* __restrict__ E)
{
    const int b   = blockIdx.x >> 6;
    const int n0  = (blockIdx.x & 63) << 6;
    const int tid = threadIdx.x;
    const int wv  = tid >> 6;
    const int lane = tid & 63;
    const int quad = lane >> 4;
    const int lc   = lane & 15;

    __shared__ unsigned short q_lds[32][72];   // +8 pad: frag reads conflict-free
    __shared__ unsigned short x_lds[64][72];

    const int n = n0 + wv * 16 + lc;

    for (int h = 0; h < 12; ++h) {
        __syncthreads();
        // stage q (pre-scaled by hd^-0.5): 32 l x 64 d
        for (int i = tid; i < 512; i += 256) {
            int l = i >> 4, f4 = i & 15;
            float4 qv = *(const float4*)&latent[l * 768 + h * 64 + f4 * 4];
            uint2 p;
            p.x = pk_bf16(qv.x * 0.125f, qv.y * 0.125f);
            p.y = pk_bf16(qv.z * 0.125f, qv.w * 0.125f);
            *(uint2*)&q_lds[l][f4 * 4] = p;
        }
        // stage x head-slice: 64 n x 64 d
        for (int i = tid; i < 1024; i += 256) {
            int nn = i >> 4, f4 = i & 15;
            float4 xv = *(const float4*)&x[(b * 4096 + n0 + nn) * 768 + h * 64 + f4 * 4];
            uint2 p;
            p.x = pk_bf16(xv.x, xv.y);
            p.y = pk_bf16(xv.z, xv.w);
            *(uint2*)&x_lds[nn][f4 * 4] = p;
        }
        __syncthreads();

        bf16x8 a00 = *(const bf16x8*)&q_lds[lc][quad * 8];
        bf16x8 a01 = *(const bf16x8*)&q_lds[lc][32 + quad * 8];
        bf16x8 a10 = *(const bf16x8*)&q_lds[16 + lc][quad * 8];
        bf16x8 a11 = *(const bf16x8*)&q_lds[16 + lc][32 + quad * 8];
        bf16x8 b0  = *(const bf16x8*)&x_lds[wv * 16 + lc][quad * 8];
        bf16x8 b1  = *(const bf16x8*)&x_lds[wv * 16 + lc][32 + quad * 8];

        f32x4 c0 = {0.f, 0.f, 0.f, 0.f};
        f32x4 c1 = {0.f, 0.f, 0.f, 0.f};
        c0 = MFMA16(a00, b0, c0);
        c0 = MFMA16(a01, b1, c0);
        c1 = MFMA16(a10, b0, c1);
        c1 = MFMA16(a11, b1, c1);

        unsigned short* Eh = E + (size_t)((b * 12 + h) * 32) * 4096;
        #pragma unroll
        for (int r = 0; r < 4; ++r) {
            // |S| <~ 0.2: exp without max-subtraction is exact softmax math
            Eh[(quad * 4 + r) * 4096 + n]      = bf16_trunc(__expf(c0[r]));
            Eh[(16 + quad * 4 + r) * 4096 + n] = bf16_trunc(__expf(c1[r]));
        }
    }
}

// ---------------------------------------------------------------------------
// KW: block = (b,l), 256 thr. Phase 1: sums[h] = sum_n E[b,h,l,n].
// Phase 2: W[b,l,n] = sum_h E * 1/(12*sums[h]). Second E read is L2-hot
// (96 KB/block). No atomics anywhere.
// ---------------------------------------------------------------------------
__global__ __launch_bounds__(256)
void kw_weights(const unsigned short* __restrict__ E, unsigned short* __restrict__ W)
{
    const int b = blockIdx.x >> 5;
    const int l = blockIdx.x & 31;
    const int tid = threadIdx.x;
    const int wv = tid >> 6, lane = tid & 63;

    const unsigned short* Eb = E + (size_t)(b * 384 + l) * 4096;  // +h*32*4096
    __shared__ float red[12][4];
    __shared__ float rsl[12];

    float s[12];
    #pragma unroll
    for (int h = 0; h < 12; ++h) {
        const uint4* p = (const uint4*)(Eb + (size_t)h * 131072 + tid * 16);
        uint4 u0 = p[0], u1 = p[1];
        float v = 0.f;
        v += bf16_lo(u0.x) + bf16_hi(u0.x) + bf16_lo(u0.y) + bf16_hi(u0.y);
        v += bf16_lo(u0.z) + bf16_hi(u0.z) + bf16_lo(u0.w) + bf16_hi(u0.w);
        v += bf16_lo(u1.x) + bf16_hi(u1.x) + bf16_lo(u1.y) + bf16_hi(u1.y);
        v += bf16_lo(u1.z) + bf16_hi(u1.z) + bf16_lo(u1.w) + bf16_hi(u1.w);
        #pragma unroll
        for (int m = 1; m < 64; m <<= 1) v += __shfl_xor(v, m);
        s[h] = v;
    }
    if (lane == 0) {
        #pragma unroll
        for (int h = 0; h < 12; ++h) red[h][wv] = s[h];
    }
    __syncthreads();
    if (tid < 12) rsl[tid] = 1.0f / (12.0f * (red[tid][0] + red[tid][1] + red[tid][2] + red[tid][3]));
    __syncthreads();

    float acc[16];
    #pragma unroll
    for (int i = 0; i < 16; ++i) acc[i] = 0.f;
    #pragma unroll
    for (int h = 0; h < 12; ++h) {
        float r = rsl[h];
        const uint4* p = (const uint4*)(Eb + (size_t)h * 131072 + tid * 16);
        uint4 u0 = p[0], u1 = p[1];
        acc[0] += bf16_lo(u0.x) * r;  acc[1] += bf16_hi(u0.x) * r;
        acc[2] += bf16_lo(u0.y) * r;  acc[3] += bf16_hi(u0.y) * r;
        acc[4] += bf16_lo(u0.z) * r;  acc[5] += bf16_hi(u0.z) * r;
        acc[6] += bf16_lo(u0.w) * r;  acc[7] += bf16_hi(u0.w) * r;
        acc[8] += bf16_lo(u1.x) * r;  acc[9] += bf16_hi(u1.x) * r;
        acc[10] += bf16_lo(u1.y) * r; acc[11] += bf16_hi(u1.y) * r;
        acc[12] += bf16_lo(u1.z) * r; acc[13] += bf16_hi(u1.z) * r;
        acc[14] += bf16_lo(u1.w) * r; acc[15] += bf16_hi(u1.w) * r;
    }
    uint4 o0, o1;
    o0.x = pk_bf16(acc[0], acc[1]);   o0.y = pk_bf16(acc[2], acc[3]);
    o0.z = pk_bf16(acc[4], acc[5]);   o0.w = pk_bf16(acc[6], acc[7]);
    o1.x = pk_bf16(acc[8], acc[9]);   o1.y = pk_bf16(acc[10], acc[11]);
    o1.z = pk_bf16(acc[12], acc[13]); o1.w = pk_bf16(acc[14], acc[15]);
    uint4* wp = (uint4*)(W + (size_t)(b * 32 + l) * 4096 + tid * 16);
    wp[0] = o0; wp[1] = o1;
}

// ---------------------------------------------------------------------------
// K3: y[g][b][l][c] = sum_{n in g*512..+512} W[b][l][n] * x[b][n][c]
// Single-wave blocks, no LDS/barriers. A-frags: 16B loads from W (L2-hot).
// B-frags: 8 scalar f32 loads (4 dense 64B lines/instr) + 4 v_perm packs.
// grid = 32 b * 12 c-tiles * 8 n-groups = 3072 blocks of 64 (12 waves/CU).
// ---------------------------------------------------------------------------
__global__ __launch_bounds__(64)
void yacc_kernel(const float* __restrict__ x, const unsigned short* __restrict__ W,
                 float* __restrict__ yws)
{
    const int bx  = blockIdx.x;
    const int b   = bx / 96;
    const int rem = bx - b * 96;
    const int ct  = rem % 12;
    const int g   = rem / 12;
    const int lane = threadIdx.x;
    const int quad = lane >> 4;
    const int lc   = lane & 15;
    const int c0   = ct * 64;
    const int nb   = g * 512;

    const float* xb = x + (size_t)b * 4096 * 768;
    const unsigned short* Wb = W + (size_t)b * 32 * 4096;

    f32x4 acc[2][4];
    #pragma unroll
    for (int t = 0; t < 2; ++t)
        #pragma unroll
        for (int s = 0; s < 4; ++s) acc[t][s] = (f32x4){0.f, 0.f, 0.f, 0.f};

    for (int kk = 0; kk < 512; kk += 32) {
        const int n = nb + kk + quad * 8;
        bf16x8 a0 = *(const bf16x8*)&Wb[lc * 4096 + n];
        bf16x8 a1 = *(const bf16x8*)&Wb[(16 + lc) * 4096 + n];
        #pragma unroll
        for (int s = 0; s < 4; ++s) {
            const float* xp = xb + (size_t)n * 768 + c0 + s * 16 + lc;
            float f0 = xp[0], f1 = xp[768], f2 = xp[1536], f3 = xp[2304];
            float f4 = xp[3072], f5 = xp[3840], f6 = xp[4608], f7 = xp[5376];
            union { uint32_t u[4]; bf16x8 v; } bb;
            bb.u[0] = pk_bf16(f0, f1);
            bb.u[1] = pk_bf16(f2, f3);
            bb.u[2] = pk_bf16(f4, f5);
            bb.u[3] = pk_bf16(f6, f7);
            acc[0][s] = MFMA16(a0, bb.v, acc[0][s]);
            acc[1][s] = MFMA16(a1, bb.v, acc[1][s]);
        }
    }

    float* yp = yws + (size_t)((g * 32 + b) * 32) * 768;
    #pragma unroll
    for (int t = 0; t < 2; ++t)
        #pragma unroll
        for (int s = 0; s < 4; ++s)
            #pragma unroll
            for (int r = 0; r < 4; ++r)
                yp[(t * 16 + quad * 4 + r) * 768 + c0 + s * 16 + lc] = acc[t][s][r];
}

// ---------------------------------------------------------------------------
// K4: out[b, l*24+i] = sum_c (sum_g y[g,b,l,c]) * v_w[l*24+i, c] + v_b
// ---------------------------------------------------------------------------
__global__ __launch_bounds__(256)
void out_kernel(const float* __restrict__ yws, const float* __restrict__ vw,
                const float* __restrict__ vb, float* __restrict__ out)
{
    const int b = blockIdx.x >> 5;
    const int l = blockIdx.x & 31;
    const int tid = threadIdx.x;
    __shared__ float y_lds[768];
    for (int c = tid; c < 768; c += 256) {
        float v = 0.f;
        #pragma unroll
        for (int g = 0; g < 8; ++g)
            v += yws[(size_t)((g * 32 + b) * 32 + l) * 768 + c];
        y_lds[c] = v;
    }
    __syncthreads();
    const int wv = tid >> 6, lane = tid & 63;
    for (int i = wv; i < 24; i += 4) {
        const int row = l * 24 + i;
        const float* wr = vw + row * 768;
        float p = 0.f;
        #pragma unroll
        for (int j = 0; j < 12; ++j)
            p += y_lds[j * 64 + lane] * wr[j * 64 + lane];
        #pragma unroll
        for (int m = 1; m < 64; m <<= 1) p += __shfl_xor(p, m);
        if (lane == 0) out[b * 768 + row] = p + vb[row];
    }
}

// ---------------------------------------------------------------------------
extern "C" void kernel_launch(void* const* d_in, const int* in_sizes, int n_in,
                              void* d_out, int out_size, void* d_ws, size_t ws_size,
                              hipStream_t stream)
{
    const float* x      = (const float*)d_in[0];  // [32,4096,768]
    const float* latent = (const float*)d_in[1];  // [1,32,768]
    const float* vw     = (const float*)d_in[2];  // [768,768]
    const float* vb     = (const float*)d_in[3];  // [768]
    float* out = (float*)d_out;                   // [32,768]

    // ws layout (~134 MB; ws_size ~1.6 GB):
    //   [0, 100663296)            E   bf16[32][12][32][4096]
    //   [100663296, 109051904)    W   bf16[32][32][4096]
    //   [109051904, 134217728)    y   f32[8][32][32][768]
    char* ws = (char*)d_ws;
    unsigned short* E   = (unsigned short*)ws;
    unsigned short* W   = (unsigned short*)(ws + 100663296);
    float*          yws = (float*)(ws + 109051904);

    k1_logits<<<dim3(2048), dim3(256), 0, stream>>>(x, latent, E);
    kw_weights<<<dim3(1024), dim3(256), 0, stream>>>(E, W);
    yacc_kernel<<<dim3(3072), dim3(64), 0, stream>>>(x, W, yws);
    out_kernel<<<dim3(1024), dim3(256), 0, stream>>>(yws, vw, vb, out);
}